// Round 4
// baseline (105.214 us; speedup 1.0000x reference)
//
#include <hip/hip_runtime.h>

typedef __bf16 bf16x8 __attribute__((ext_vector_type(8)));
typedef float f32x4 __attribute__((ext_vector_type(4)));

// Problem constants: B=4, Cin=64, Cout=64, H=W=128, K=3, PAD=1, KK=9

// ---------------- Kernel 1: x (NCHW f32) -> x_t (NHWC bf16) ----------------
__global__ __launch_bounds__(256) void k_xt(const float* __restrict__ x,
                                            __bf16* __restrict__ xt) {
  __shared__ float tile[64 * 129];
  int b = blockIdx.x >> 7;
  int y = blockIdx.x & 127;
  int t = threadIdx.x;
#pragma unroll
  for (int it = 0; it < 32; ++it) {
    int r = it * 256 + t;           // 8192 elems: 64c x 128w
    int c = r >> 7, xw = r & 127;
    tile[c * 129 + xw] = x[((b * 64 + c) * 128 + y) * 128 + xw];
  }
  __syncthreads();
#pragma unroll
  for (int it = 0; it < 32; ++it) {
    int r = it * 256 + t;
    int xw = r >> 6, c = r & 63;
    xt[((b * 128 + y) * 128 + xw) * 64 + c] = (__bf16)tile[c * 129 + xw];
  }
}

// ------- Kernel 2: weight preps (merged) -------
// wb[k][o][c] from wt(O,C,3,3); owb[k][32pad][c] from ow(18,C,3,3)
__global__ __launch_bounds__(256) void k_prep(const float* __restrict__ wt,
                                              const float* __restrict__ ow,
                                              __bf16* __restrict__ wb,
                                              __bf16* __restrict__ owb) {
  int i = blockIdx.x * 256 + threadIdx.x;
  if (i < 36864) {
    int k = i >> 12, rem = i & 4095, o = rem >> 6, c = rem & 63;
    wb[i] = (__bf16)wt[(o * 64 + c) * 9 + k];
  } else if (i < 36864 + 18432) {
    int j = i - 36864;
    int k = j >> 11, rem = j & 2047, o = rem >> 6, c = rem & 63;
    float v = (o < 18) ? ow[(o * 64 + c) * 9 + k] : 0.0f;
    owb[j] = (__bf16)v;
  }
}

// ---------------- Kernel 3: fully fused deformable conv ----------------
// grid: 1024 blocks = (2 wtiles) x (128 h) x (4 b); 256 threads (4 waves)
// Phase A: offset conv (M=18pad32, N=64 pix, K=576) -> offL in LDS, 1 barrier
// Phase B: NO LDS, NO barriers. Each wave owns 16 pixels x all 64 out-channels.
//   Lane samples pixel (lane&15) at channels quad*8 and 32+quad*8 -> the two
//   B-fragments directly; A-fragments stream from L1-hot wb.
__global__ __launch_bounds__(256, 4) void k_fused(
    const __bf16* __restrict__ xt, const __bf16* __restrict__ wb,
    const __bf16* __restrict__ owb, const float* __restrict__ ob,
    const float* __restrict__ bias, float* __restrict__ out) {
  __shared__ float offL[64 * 20];  // [pix][co<18], stride 20

  int t = threadIdx.x;
  int wtile = blockIdx.x & 1;
  int h = (blockIdx.x >> 1) & 127;
  int b = blockIdx.x >> 8;
  int w0 = wtile * 64;

  int lane = t & 63, wid = t >> 6;
  int row = lane & 15, quad = lane >> 4;

  const __bf16* xb = xt + (size_t)b * 128 * 128 * 64;
  bf16x8 zero = {};

  // ================= Phase A: offset conv =================
  {
    int woA = (wid >> 1) * 16;  // o-base: 0 or 16
    int wpA = (wid & 1) * 32;   // pix-base: 0 or 32
    f32x4 accA[2];
    accA[0] = f32x4{0.f, 0.f, 0.f, 0.f};
    accA[1] = f32x4{0.f, 0.f, 0.f, 0.f};
    for (int k = 0; k < 9; ++k) {
      int ki = k / 3, kj = k % 3;
      int hh = h + ki - 1;
      if ((unsigned)hh >= 128u) continue;  // uniform: zero row contributes 0
      const __bf16* ap = owb + k * 2048 + (woA + row) * 64 + quad * 8;
      bf16x8 afr0 = *(const bf16x8*)(ap);
      bf16x8 afr1 = *(const bf16x8*)(ap + 32);
#pragma unroll
      for (int n = 0; n < 2; ++n) {
        int gx = w0 + wpA + n * 16 + row + kj - 1;
        bool oob = (unsigned)gx >= 128u;
        int gxc = min(max(gx, 0), 127);
        const __bf16* p = xb + (hh * 128 + gxc) * 64 + quad * 8;
        bf16x8 b0 = *(const bf16x8*)(p);
        bf16x8 b1 = *(const bf16x8*)(p + 32);
        if (oob) { b0 = zero; b1 = zero; }
        accA[n] = __builtin_amdgcn_mfma_f32_16x16x32_bf16(afr0, b0, accA[n], 0, 0, 0);
        accA[n] = __builtin_amdgcn_mfma_f32_16x16x32_bf16(afr1, b1, accA[n], 0, 0, 0);
      }
    }
    // epilogue to LDS: C/D layout col=lane&15 (pix), row=quad*4+r (o)
    int qr = quad * 4;
#pragma unroll
    for (int n = 0; n < 2; ++n) {
#pragma unroll
      for (int r = 0; r < 4; ++r) {
        int co = woA + qr + r;
        if (co < 18)
          offL[(wpA + n * 16 + row) * 20 + co] = accA[n][r] + ob[co];
      }
    }
  }
  __syncthreads();

  // ================= Phase B: sampling + main GEMM, barrier-free =================
  // Wave wid owns pixels [wid*16, wid*16+16); lane's pixel = wid*16 + row.
  int pixw = wid * 16 + row;
  int w = w0 + pixw;

  f32x4 acc[4];  // o-frags 0..3 (o = mi*16 + quad*4 + r), pixel col = row
#pragma unroll
  for (int i = 0; i < 4; ++i) acc[i] = f32x4{0.f, 0.f, 0.f, 0.f};

  for (int k = 0; k < 9; ++k) {
    int ki = k / 3, kj = k % 3;
    // ---- sample 16 channels (quad*8 and 32+quad*8) at this lane's pixel ----
    float dy = offL[pixw * 20 + 2 * k];
    float dx = offL[pixw * 20 + 2 * k + 1];
    float py = dy + (float)(h + ki - 1);
    float px = dx + (float)(w + kj - 1);
    float fy = floorf(py), fx = floorf(px);
    float ly = py - fy, lx = px - fx;
    int y0 = (int)fy, x0 = (int)fx;
    int y1 = y0 + 1, x1 = x0 + 1;
    bool vy0 = (unsigned)y0 < 128u, vy1 = (unsigned)y1 < 128u;
    bool vx0 = (unsigned)x0 < 128u, vx1 = (unsigned)x1 < 128u;
    float w00 = (vy0 && vx0) ? (1.f - ly) * (1.f - lx) : 0.f;
    float w01 = (vy0 && vx1) ? (1.f - ly) * lx : 0.f;
    float w10 = (vy1 && vx0) ? ly * (1.f - lx) : 0.f;
    float w11 = (vy1 && vx1) ? ly * lx : 0.f;
    int yc0 = min(max(y0, 0), 127), yc1 = min(max(y1, 0), 127);
    int xc0 = min(max(x0, 0), 127), xc1 = min(max(x1, 0), 127);
    const __bf16* xc = xb + quad * 8;  // ch-group ks0: quad*8, ks1: +32
    const __bf16* p00 = xc + (yc0 * 128 + xc0) * 64;
    const __bf16* p01 = xc + (yc0 * 128 + xc1) * 64;
    const __bf16* p10 = xc + (yc1 * 128 + xc0) * 64;
    const __bf16* p11 = xc + (yc1 * 128 + xc1) * 64;
    bf16x8 a00 = *(const bf16x8*)p00, b00 = *(const bf16x8*)(p00 + 32);
    bf16x8 a01 = *(const bf16x8*)p01, b01 = *(const bf16x8*)(p01 + 32);
    bf16x8 a10 = *(const bf16x8*)p10, b10 = *(const bf16x8*)(p10 + 32);
    bf16x8 a11 = *(const bf16x8*)p11, b11 = *(const bf16x8*)(p11 + 32);
    bf16x8 s0, s1;  // B-fragments for ks=0 (ch quad*8) and ks=1 (ch 32+quad*8)
#pragma unroll
    for (int j = 0; j < 8; ++j) {
      float v0 = w00 * (float)a00[j] + w01 * (float)a01[j] +
                 w10 * (float)a10[j] + w11 * (float)a11[j];
      float v1 = w00 * (float)b00[j] + w01 * (float)b01[j] +
                 w10 * (float)b10[j] + w11 * (float)b11[j];
      s0[j] = (__bf16)v0;
      s1[j] = (__bf16)v1;
    }
    // ---- MFMA: acc[mi] += W_k[o-frag mi][ch] * s, A direct from L1-hot wb ----
    const __bf16* wk = wb + k * 4096 + row * 64 + quad * 8;
#pragma unroll
    for (int mi = 0; mi < 4; ++mi) {
      bf16x8 af0 = *(const bf16x8*)(wk + mi * 16 * 64);
      bf16x8 af1 = *(const bf16x8*)(wk + mi * 16 * 64 + 32);
      acc[mi] = __builtin_amdgcn_mfma_f32_16x16x32_bf16(af0, s0, acc[mi], 0, 0, 0);
      acc[mi] = __builtin_amdgcn_mfma_f32_16x16x32_bf16(af1, s1, acc[mi], 0, 0, 0);
    }
  }
  // ---- epilogue: col=lane&15 (pixel), row=quad*4+r (o within frag) ----
  {
    int qr = quad * 4;
#pragma unroll
    for (int mi = 0; mi < 4; ++mi) {
#pragma unroll
      for (int r = 0; r < 4; ++r) {
        int o = mi * 16 + qr + r;
        out[((b * 64 + o) * 128 + h) * 128 + w0 + wid * 16 + row] =
            acc[mi][r] + bias[o];
      }
    }
  }
}

extern "C" void kernel_launch(void* const* d_in, const int* in_sizes, int n_in,
                              void* d_out, int out_size, void* d_ws,
                              size_t ws_size, hipStream_t stream) {
  const float* x = (const float*)d_in[0];       // (4,64,128,128)
  const float* ow = (const float*)d_in[1];      // (18,64,3,3)
  const float* ob = (const float*)d_in[2];      // (18,)
  const float* wt = (const float*)d_in[3];      // (64,64,3,3)
  const float* bias = (const float*)d_in[4];    // (64,)
  float* out = (float*)d_out;                   // (4,64,128,128)

  char* ws = (char*)d_ws;
  __bf16* xt = (__bf16*)ws;                     // 8,388,608 B
  __bf16* wb = (__bf16*)(ws + 8388608);         // 73,728 B
  __bf16* owb = (__bf16*)(ws + 8388608 + 73728);// 36,864 B

  k_xt<<<512, 256, 0, stream>>>(x, xt);
  k_prep<<<216, 256, 0, stream>>>(wt, ow, wb, owb);
  k_fused<<<1024, 256, 0, stream>>>(xt, wb, owb, ob, bias, out);
}

// Round 5
// 57.925 us; speedup vs baseline: 1.8164x; 1.8164x over previous
//
#include <hip/hip_runtime.h>

typedef __bf16 bf16x8 __attribute__((ext_vector_type(8)));
typedef float f32x4 __attribute__((ext_vector_type(4)));

// Problem constants: B=4, Cin=64, Cout=64, H=W=128, K=3, PAD=1, KK=9

// ---------------- Kernel 1: x (NCHW f32) -> x_t (NHWC bf16) ----------------
__global__ __launch_bounds__(256) void k_xt(const float* __restrict__ x,
                                            __bf16* __restrict__ xt) {
  __shared__ float tile[64 * 129];
  int b = blockIdx.x >> 7;
  int y = blockIdx.x & 127;
  int t = threadIdx.x;
#pragma unroll
  for (int it = 0; it < 32; ++it) {
    int r = it * 256 + t;           // 8192 elems: 64c x 128w
    int c = r >> 7, xw = r & 127;
    tile[c * 129 + xw] = x[((b * 64 + c) * 128 + y) * 128 + xw];
  }
  __syncthreads();
#pragma unroll
  for (int it = 0; it < 32; ++it) {
    int r = it * 256 + t;
    int xw = r >> 6, c = r & 63;
    xt[((b * 128 + y) * 128 + xw) * 64 + c] = (__bf16)tile[c * 129 + xw];
  }
}

// ------- Kernel 2: weight preps (merged) -------
// wb[k][o][c] from wt(O,C,3,3); owb[k][32pad][c] from ow(18,C,3,3)
__global__ __launch_bounds__(256) void k_prep(const float* __restrict__ wt,
                                              const float* __restrict__ ow,
                                              __bf16* __restrict__ wb,
                                              __bf16* __restrict__ owb) {
  int i = blockIdx.x * 256 + threadIdx.x;
  if (i < 36864) {
    int k = i >> 12, rem = i & 4095, o = rem >> 6, c = rem & 63;
    wb[i] = (__bf16)wt[(o * 64 + c) * 9 + k];
  } else if (i < 36864 + 18432) {
    int j = i - 36864;
    int k = j >> 11, rem = j & 2047, o = rem >> 6, c = rem & 63;
    float v = (o < 18) ? ow[(o * 64 + c) * 9 + k] : 0.0f;
    owb[j] = (__bf16)v;
  }
}

// ---------------- Kernel 3: fully fused deformable conv ----------------
// grid: 1024 blocks = (2 wtiles) x (128 h) x (4 b); 256 threads (4 waves)
// Stage0: raw 3-row x 66-pix x 64c bf16 tile -> LDS (zero-padded, branch-free)
// Phase A: offset conv MFMA, B-frags from LDS (no global x reads, full unroll)
// Phase B: per tap: bilinear-sample S tile -> LDS, barriered MFMA (round-3 proven)
__global__ __launch_bounds__(256) void k_fused(
    const __bf16* __restrict__ xt, const __bf16* __restrict__ wb,
    const __bf16* __restrict__ owb, const float* __restrict__ ob,
    const float* __restrict__ bias, float* __restrict__ out) {
  // LDS union: Xs [3][66][72] (28512 B) overlapped by S [64][72] (9216 B);
  // offL [64][20] f32 (5120 B) disjoint. Total 33632 B -> 4 blocks/CU.
  __shared__ char ldsraw[3 * 66 * 72 * 2 + 64 * 20 * 4];
  __bf16* Xs = (__bf16*)ldsraw;
  __bf16* S = (__bf16*)ldsraw;                 // reused after Phase A
  float* offL = (float*)(ldsraw + 28512);

  int t = threadIdx.x;
  int wtile = blockIdx.x & 1;
  int h = (blockIdx.x >> 1) & 127;
  int b = blockIdx.x >> 8;
  int w0 = wtile * 64;

  int lane = t & 63, wid = t >> 6;
  int row = lane & 15, quad = lane >> 4;

  const __bf16* xb = xt + (size_t)b * 128 * 128 * 64;

  // ======= Stage0: raw tile rows h-1..h+1, pixels w0-1..w0+64, all 64c =======
  {
#pragma unroll
    for (int it = 0; it < 7; ++it) {
      int idx8 = it * 256 + t;                 // 1584 chunks of 8 elems
      if (idx8 < 1584) {
        int c8 = idx8 & 7;
        int jr = idx8 >> 3;                    // 0..197
        int jj = jr % 66;
        int ki = jr / 66;
        int gy = h - 1 + ki;
        int gx = w0 - 1 + jj;
        bf16x8 v = {};
        if (((unsigned)gy < 128u) & ((unsigned)gx < 128u))
          v = *(const bf16x8*)(xb + (gy * 128 + gx) * 64 + c8 * 8);
        *(bf16x8*)&Xs[(ki * 66 + jj) * 72 + c8 * 8] = v;
      }
    }
  }
  __syncthreads();

  // ================= Phase A: offset conv, B from LDS =================
  {
    int woA = (wid >> 1) * 16;  // o-base: 0 or 16
    int wpA = (wid & 1) * 32;   // pix-base: 0 or 32
    f32x4 accA[2];
    accA[0] = f32x4{0.f, 0.f, 0.f, 0.f};
    accA[1] = f32x4{0.f, 0.f, 0.f, 0.f};
#pragma unroll
    for (int k = 0; k < 9; ++k) {
      int ki = k / 3, kj = k % 3;
      const __bf16* ap = owb + k * 2048 + (woA + row) * 64 + quad * 8;
      bf16x8 afr0 = *(const bf16x8*)(ap);
      bf16x8 afr1 = *(const bf16x8*)(ap + 32);
#pragma unroll
      for (int n = 0; n < 2; ++n) {
        int j = wpA + n * 16 + row + kj;       // 0..65
        const __bf16* lp = &Xs[(ki * 66 + j) * 72 + quad * 8];
        bf16x8 b0 = *(const bf16x8*)(lp);
        bf16x8 b1 = *(const bf16x8*)(lp + 32);
        accA[n] = __builtin_amdgcn_mfma_f32_16x16x32_bf16(afr0, b0, accA[n], 0, 0, 0);
        accA[n] = __builtin_amdgcn_mfma_f32_16x16x32_bf16(afr1, b1, accA[n], 0, 0, 0);
      }
    }
    // epilogue to LDS: C/D layout col=lane&15 (pix), row=quad*4+r (o)
    int qr = quad * 4;
#pragma unroll
    for (int n = 0; n < 2; ++n) {
#pragma unroll
      for (int r = 0; r < 4; ++r) {
        int co = woA + qr + r;
        if (co < 18)
          offL[(wpA + n * 16 + row) * 20 + co] = accA[n][r] + ob[co];
      }
    }
  }
  __syncthreads();

  // ================= Phase B: sampling + main GEMM (round-3 proven) =================
  int pix = t >> 2;  // 0..63
  int cg = t & 3;    // c-group of 16
  int w = w0 + pix;
  int woB = (wid >> 1) * 32;
  int wpB = (wid & 1) * 32;

  f32x4 acc[2][2];
#pragma unroll
  for (int i = 0; i < 2; ++i)
#pragma unroll
    for (int j = 0; j < 2; ++j) acc[i][j] = f32x4{0.f, 0.f, 0.f, 0.f};

  for (int k = 0; k < 9; ++k) {
    // ---- compute sampled tile S[pix][c] for this k ----
    {
      int ki = k / 3, kj = k % 3;
      float dy = offL[pix * 20 + 2 * k];
      float dx = offL[pix * 20 + 2 * k + 1];
      float py = dy + (float)(h + ki - 1);
      float px = dx + (float)(w + kj - 1);
      float fy = floorf(py), fx = floorf(px);
      float ly = py - fy, lx = px - fx;
      int y0 = (int)fy, x0 = (int)fx;
      int y1 = y0 + 1, x1 = x0 + 1;
      bool vy0 = (unsigned)y0 < 128u, vy1 = (unsigned)y1 < 128u;
      bool vx0 = (unsigned)x0 < 128u, vx1 = (unsigned)x1 < 128u;
      float w00 = (vy0 && vx0) ? (1.f - ly) * (1.f - lx) : 0.f;
      float w01 = (vy0 && vx1) ? (1.f - ly) * lx : 0.f;
      float w10 = (vy1 && vx0) ? ly * (1.f - lx) : 0.f;
      float w11 = (vy1 && vx1) ? ly * lx : 0.f;
      int yc0 = min(max(y0, 0), 127), yc1 = min(max(y1, 0), 127);
      int xc0 = min(max(x0, 0), 127), xc1 = min(max(x1, 0), 127);
      const __bf16* xc = xb + cg * 16;
      const bf16x8* p00 = (const bf16x8*)(xc + (yc0 * 128 + xc0) * 64);
      const bf16x8* p01 = (const bf16x8*)(xc + (yc0 * 128 + xc1) * 64);
      const bf16x8* p10 = (const bf16x8*)(xc + (yc1 * 128 + xc0) * 64);
      const bf16x8* p11 = (const bf16x8*)(xc + (yc1 * 128 + xc1) * 64);
      bf16x8 a00 = p00[0], b00 = p00[1];
      bf16x8 a01 = p01[0], b01 = p01[1];
      bf16x8 a10 = p10[0], b10 = p10[1];
      bf16x8 a11 = p11[0], b11 = p11[1];
      bf16x8 o0, o1;
#pragma unroll
      for (int j = 0; j < 8; ++j) {
        float s0 = w00 * (float)a00[j] + w01 * (float)a01[j] +
                   w10 * (float)a10[j] + w11 * (float)a11[j];
        float s1 = w00 * (float)b00[j] + w01 * (float)b01[j] +
                   w10 * (float)b10[j] + w11 * (float)b11[j];
        o0[j] = (__bf16)s0;
        o1[j] = (__bf16)s1;
      }
      *(bf16x8*)&S[pix * 72 + cg * 16] = o0;
      *(bf16x8*)&S[pix * 72 + cg * 16 + 8] = o1;
    }
    __syncthreads();
    // ---- MFMA: acc += W_k[o][c] * S[pix][c], A-frags direct from L1-hot wb ----
    {
      const __bf16* wk = wb + k * 4096;
#pragma unroll
      for (int ks = 0; ks < 2; ++ks) {
        int c0 = ks * 32 + quad * 8;
        bf16x8 afr[2], bfr[2];
#pragma unroll
        for (int mi = 0; mi < 2; ++mi)
          afr[mi] = *(const bf16x8*)(wk + (woB + mi * 16 + row) * 64 + c0);
#pragma unroll
        for (int ni = 0; ni < 2; ++ni)
          bfr[ni] = *(const bf16x8*)&S[(wpB + ni * 16 + row) * 72 + c0];
#pragma unroll
        for (int mi = 0; mi < 2; ++mi)
#pragma unroll
          for (int ni = 0; ni < 2; ++ni)
            acc[mi][ni] = __builtin_amdgcn_mfma_f32_16x16x32_bf16(
                afr[mi], bfr[ni], acc[mi][ni], 0, 0, 0);
      }
    }
    __syncthreads();
  }
  // ---- epilogue: col=lane&15 (pix), row=(lane>>4)*4+reg (o) ----
  {
    int col = lane & 15;
    int qr = quad * 4;
#pragma unroll
    for (int mi = 0; mi < 2; ++mi) {
#pragma unroll
      for (int ni = 0; ni < 2; ++ni) {
#pragma unroll
        for (int r = 0; r < 4; ++r) {
          int o = woB + mi * 16 + qr + r;
          int pw = w0 + wpB + ni * 16 + col;
          out[((b * 64 + o) * 128 + h) * 128 + pw] = acc[mi][ni][r] + bias[o];
        }
      }
    }
  }
}

extern "C" void kernel_launch(void* const* d_in, const int* in_sizes, int n_in,
                              void* d_out, int out_size, void* d_ws,
                              size_t ws_size, hipStream_t stream) {
  const float* x = (const float*)d_in[0];       // (4,64,128,128)
  const float* ow = (const float*)d_in[1];      // (18,64,3,3)
  const float* ob = (const float*)d_in[2];      // (18,)
  const float* wt = (const float*)d_in[3];      // (64,64,3,3)
  const float* bias = (const float*)d_in[4];    // (64,)
  float* out = (float*)d_out;                   // (4,64,128,128)

  char* ws = (char*)d_ws;
  __bf16* xt = (__bf16*)ws;                     // 8,388,608 B
  __bf16* wb = (__bf16*)(ws + 8388608);         // 73,728 B
  __bf16* owb = (__bf16*)(ws + 8388608 + 73728);// 36,864 B

  k_xt<<<512, 256, 0, stream>>>(x, xt);
  k_prep<<<216, 256, 0, stream>>>(wt, ow, wb, owb);
  k_fused<<<1024, 256, 0, stream>>>(xt, wb, owb, ob, bias, out);
}